// Round 11
// baseline (2737.077 us; speedup 1.0000x reference)
//
#include <hip/hip_runtime.h>
#include <hip/hip_bf16.h>

#define H_ 8
#define NTOT 8192
#define LG 1024
#define BN 8
#define HD 16
#define DSTATE 64
#define EPG 16384
#define MSZ (1024*1024)

typedef __hip_bfloat16 bf16;
typedef unsigned short ushort_t;
typedef _Float16 f16;
typedef __attribute__((ext_vector_type(8))) _Float16 half8;
typedef __attribute__((ext_vector_type(4))) _Float16 half4;
typedef __attribute__((ext_vector_type(4))) float f4v;

__device__ __forceinline__ float b2f(bf16 v){ return __bfloat162float(v); }
// stable softplus matching jax.nn.softplus = log1p(exp(z))
__device__ __forceinline__ float sp_(float z){
  return fmaxf(z, 0.f) + log1pf(expf(-fabsf(z)));
}
// dtype-flagged scalar load (uniform branch)
__device__ __forceinline__ float ldv(const void* p, size_t i, int f32){
  float v;
  if (f32) v = ((const float*)p)[i];
  else     v = b2f(((const bf16*)p)[i]);
  return v;
}
// async global->LDS, 16 bytes per lane
__device__ __forceinline__ void gl2lds16(const void* g, void* l){
  __builtin_amdgcn_global_load_lds((const __attribute__((address_space(1))) unsigned int*)g,
                                   (__attribute__((address_space(3))) unsigned int*)l,
                                   16, 0, 0);
}

// -------- dtype sniffer: bf16 N(0,1) data never has exponent>=140; f32-as-bf16 does.
__global__ void k_sniff(const void* __restrict__ dt, int* __restrict__ flag){
  const ushort_t* p = (const ushort_t*)dt;
  int tid = threadIdx.x;
  int bad = 0;
  for (int i = tid; i < 512; i += 256){
    int e = (p[i] >> 7) & 0xFF;
    if (e >= 140) bad = 1;
  }
  unsigned long long m = __ballot(bad != 0);
  __shared__ int anybad[4];
  if ((tid & 63) == 0) anybad[tid >> 6] = (m != 0ull) ? 1 : 0;
  __syncthreads();
  if (tid == 0) *flag = (anybad[0] | anybad[1] | anybad[2] | anybad[3]);
}

// -------- per-node coefficients
__global__ void k_nodecoef(const void* __restrict__ dt, const void* __restrict__ dtb,
                           const int* __restrict__ flag,
                           float* __restrict__ a0, float* __restrict__ a1,
                           float* __restrict__ dum, float* __restrict__ sdt){
  int idx = blockIdx.x*256 + threadIdx.x;
  if (idx >= H_*NTOT) return;
  int f32 = *flag;
  int h = idx / NTOT, n = idx - h*NTOT;
  float bias = ldv(dtb, h, f32);
  size_t base = (size_t)n*(4*H_) + h*4;
  float d0, d1, d2, d3;
  if (f32){
    const float* row = (const float*)dt + base;
    d0 = row[0]; d1 = row[1]; d2 = row[2]; d3 = row[3];
  } else {
    const bf16* row = (const bf16*)dt + base;
    d0 = b2f(row[0]); d1 = b2f(row[1]); d2 = b2f(row[2]); d3 = b2f(row[3]);
  }
  a0[idx]  = -sp_(d0 + bias);
  a1[idx]  = -sp_(d1 + bias);
  dum[idx] = expf(-sp_(d2 + bias));
  sdt[idx] = d3;
}

// -------- zero the per-bh fp32 scatter buffers (aliased at f16 matrix slots 2,3)
__global__ __launch_bounds__(256) void k_zero(char* base, size_t regB){
  int bh = blockIdx.y;
  float* Mf = (float*)(base + (size_t)bh*regB) + MSZ;
  int i = blockIdx.x*1024 + threadIdx.x*4;
  *(float4*)(Mf + i) = make_float4(0.f,0.f,0.f,0.f);
}

// -------- scatter edges into fp32 M = A^T (M[dl][sl] += attr), plus row-sum of A over sl
__global__ void k_scatter(const int* __restrict__ ei, const float* __restrict__ a0,
                          const float* __restrict__ a1, char* base, size_t regB,
                          float* __restrict__ nrm,
                          int b0, int h0, int lgHB, int GBp, int nthreads, int Etot){
  int t = blockIdx.x*256 + threadIdx.x;
  if (t >= nthreads) return;
  int HB = 1 << lgHB;
  int hl = t & (HB-1);
  int el = t >> lgHB;
  int e = b0*EPG + el;
  int src = ei[e], dst = ei[Etot + e];
  int g = src >> 10;
  if ((unsigned)(g - b0) >= (unsigned)GBp) return;
  int sl = src & 1023, dl = dst & 1023;
  int h = h0 + hl;
  float attr = expf(0.5f*(a0[h*NTOT + src] + a1[h*NTOT + dst]));
  int bhl = (g - b0)*HB + hl;
  float* Mf = (float*)(base + (size_t)bhl*regB) + MSZ;
  atomicAdd(&Mf[(size_t)dl*LG + sl], attr);
  atomicAdd(&nrm[bhl*LG + sl], attr);
}

// -------- column-normalize M, write f16 L0 (slot 0) and O0 = I+M (slot 4)
__global__ void k_normalize(char* base, size_t regB,
                            const float* __restrict__ nrm, const float* __restrict__ dum,
                            int b0, int h0, int HB){
  size_t idx = (size_t)blockIdx.x*256 + threadIdx.x;
  int bh = (int)(idx >> 20);
  int rem = (int)(idx & (MSZ-1));
  int sl = rem & 1023, dl = rem >> 10;
  int g = b0 + bh / HB, h = h0 + bh % HB;
  const float* Mf = (const float*)(base + (size_t)bh*regB) + MSZ;
  f16* ub = (f16*)(base + (size_t)bh*regB);
  float denom = nrm[bh*LG + sl] + dum[h*NTOT + g*LG + sl] + 0.1f;
  float v = Mf[rem] / denom;
  ub[rem] = (f16)v;                                        // L0
  ub[(size_t)4*MSZ + rem] = (f16)(v + (dl == sl ? 1.f : 0.f));  // O0 = I+M
}

// -------- batched f16 transpose: slot iD = transpose(slot iS)  (only used for L0)
__global__ __launch_bounds__(256) void k_transpose(char* base, size_t regB, int iS, int iD){
  __shared__ ushort_t t[32][33];
  int bh = blockIdx.z;
  const ushort_t* S = (const ushort_t*)(base + (size_t)bh*regB) + (size_t)iS*MSZ;
  ushort_t* D = (ushort_t*)(base + (size_t)bh*regB) + (size_t)iD*MSZ;
  int x0 = blockIdx.x*32, y0 = blockIdx.y*32;
  int tx = threadIdx.x & 31, ty = threadIdx.x >> 5;  // 32 x 8
  #pragma unroll
  for (int i = 0; i < 32; i += 8)
    t[ty+i][tx] = S[(size_t)(y0+ty+i)*LG + x0+tx];
  __syncthreads();
  #pragma unroll
  for (int i = 0; i < 32; i += 8)
    D[(size_t)(x0+ty+i)*LG + y0+tx] = t[tx][ty+i];
}

// -------- G[b][l][t] = sum_d C[b,l,d]*B[b,t,d]  -> stored f16
__global__ __launch_bounds__(256) void k_G(const void* __restrict__ Bm, const void* __restrict__ Cm,
                                           const int* __restrict__ flag,
                                           f16* __restrict__ G, int b0){
  int gl = blockIdx.z;
  int g = b0 + gl;
  int l0 = blockIdx.y*16, t0 = blockIdx.x*16;
  __shared__ float Cs[16][DSTATE+1];
  __shared__ float Bs[16][DSTATE+1];
  int tid = threadIdx.x;
  int f32 = *flag;
  if (f32){
    const float* Cf = (const float*)Cm;
    const float* Bf = (const float*)Bm;
    for (int i = tid; i < 16*DSTATE; i += 256){
      int r = i >> 6, d = i & 63;
      Cs[r][d] = Cf[(size_t)(g*LG + l0 + r)*DSTATE + d];
      Bs[r][d] = Bf[(size_t)(g*LG + t0 + r)*DSTATE + d];
    }
  } else {
    const bf16* Cb = (const bf16*)Cm;
    const bf16* Bb = (const bf16*)Bm;
    for (int i = tid; i < 16*DSTATE; i += 256){
      int r = i >> 6, d = i & 63;
      Cs[r][d] = b2f(Cb[(size_t)(g*LG + l0 + r)*DSTATE + d]);
      Bs[r][d] = b2f(Bb[(size_t)(g*LG + t0 + r)*DSTATE + d]);
    }
  }
  __syncthreads();
  int r = tid >> 4, c = tid & 15;
  float acc = 0.f;
  #pragma unroll
  for (int d = 0; d < DSTATE; ++d) acc = fmaf(Cs[r][d], Bs[c][d], acc);
  G[(size_t)gl*MSZ + (size_t)(l0+r)*LG + t0 + c] = (f16)acc;
}

// -------- fused f16 MFMA GEMM dispatch (r10 shape + restructured K-loop):
// slices [0,nS) run S (square: C = A@B, writes C and C^T), slices [nS,nS+nU) run
// U (C = A@B + A). B given via its transpose slot. 128x128 block tile, 512 threads =
// 8 waves x 64x32 tiles. 3-stage rotating LDS pipeline (48 KB), BK=32 per stage.
// K-loop uses RAW s_waitcnt vmcnt(2) + s_barrier (no vmcnt(0) drain): stage k+1's
// loads stay in flight across the barrier -> 2-iteration prefetch depth, vs the
// 1-iteration depth __syncthreads() forces (it drains vmcnt to 0 every iter —
// the invariant ~100us across r8/r9/r10 shapes fingered this stall).
// Each thread issues exactly 2 global_load_lds per stage (vmcnt bookkeeping).
// XOR swizzle (r9, verified 0 conflicts): thread t fetches k-chunk (t&3)^((t>>3)&3);
// fragment reads use lane-constant slot q^((m16>>1)&3).
__global__ __launch_bounds__(512, 6) void k_gemm_fused(char* base, size_t regB,
    int nS, int iAs, int iBTs, int iCs, int iCTs,
    int nU, int iAu, int iBTu, int iCu){
  __shared__ ushort_t As[3][4096];   // [stage][128 rows x 32 k] (swizzled slots)
  __shared__ ushort_t Bs[3][4096];
  int T = nS + nU;
  int s = blockIdx.x + 8*blockIdx.z;
  if (s >= T) return;
  int isS = (s < nS) ? 1 : 0;
  int bh  = isS ? s : (s - nS);
  int iA  = isS ? iAs : iAu;
  int iBT = isS ? iBTs : iBTu;
  int iC  = isS ? iCs : iCu;
  int iCT = isS ? iCTs : -1;
  int addA = 1 - isS;
  char* reg = base + (size_t)bh*regB;
  const f16* Ab = (const f16*)reg + (size_t)iA*MSZ;
  const f16* Bb = (const f16*)reg + (size_t)iBT*MSZ;
  f16* Cb = (f16*)reg + (size_t)iC*MSZ;
  int y = blockIdx.y;
  int i0 = (y >> 3)*128, j0 = (y & 7)*128;
  int tid = threadIdx.x;
  int lane = tid & 63, wv = tid >> 6;       // 8 waves
  int wr = (wv >> 2)*64, wc = (wv & 3)*32;  // wave tile: 64 rows x 32 cols
  int m16 = lane & 15, q = lane >> 4;
  // staging: thread t fills LDS slot t (8 ushort) in A and in B; source XOR-swizzled
  int srow = tid >> 2;
  int skq = (tid & 3) ^ ((tid >> 3) & 3);
  const f16* Ag = Ab + (size_t)(i0 + srow)*LG + skq*8;
  const f16* Bg = Bb + (size_t)(j0 + srow)*LG + skq*8;
  #define STAGE(K0, BUF) do { \
    gl2lds16(Ag + (K0), &As[BUF][(size_t)tid*8]); \
    gl2lds16(Bg + (K0), &Bs[BUF][(size_t)tid*8]); } while(0)
  STAGE(0, 0);
  STAGE(32, 1);
  f4v acc[4][2] = {};
  int slotq = q ^ ((m16 >> 1) & 3);         // swizzled slot holding k-chunk q (lane-constant)
  int aoff = (wr + m16)*32 + slotq*8;       // + t*512 per 16-row tile t
  int boff = (wc + m16)*32 + slotq*8;
  int st = 0;                               // rotating stage index
  for (int k0 = 0; k0 < LG; k0 += 32){
    // wait MY stage-st loads done (allow stage st+1 in flight), then rendezvous:
    // after barrier, ALL waves' stage-st data is in LDS.
    __asm__ __volatile__("" ::: "memory");
    if (k0 == LG - 32) __builtin_amdgcn_s_waitcnt(0x0F70);  // vmcnt(0), no lgkm/exp wait
    else               __builtin_amdgcn_s_waitcnt(0x0F72);  // vmcnt(2)
    __builtin_amdgcn_s_barrier();
    __asm__ __volatile__("" ::: "memory");
    if (k0 + 64 < LG){
      int nb = st - 1; if (nb < 0) nb = 2;  // (st+2)%3: buffer consumed at iter k-1
      STAGE(k0 + 64, nb);
    }
    half8 af[4], bfr[2];
    #pragma unroll
    for (int t = 0; t < 4; ++t)
      af[t]  = *(const half8*)&As[st][aoff + t*512];
    #pragma unroll
    for (int t = 0; t < 2; ++t)
      bfr[t] = *(const half8*)&Bs[st][boff + t*512];
    #pragma unroll
    for (int mt = 0; mt < 4; ++mt)
      #pragma unroll
      for (int nt = 0; nt < 2; ++nt)
        acc[mt][nt] = __builtin_amdgcn_mfma_f32_16x16x32_f16(af[mt], bfr[nt], acc[mt][nt], 0, 0, 0);
    st = (st == 2) ? 0 : st + 1;
  }
  #undef STAGE
  f16* CT = (f16*)reg + (size_t)((iCT < 0) ? iC : iCT)*MSZ;
  // epilogue: D lane mapping col=lane&15, row=(lane>>4)*4+r
  #pragma unroll
  for (int mt = 0; mt < 4; ++mt){
    #pragma unroll
    for (int nt = 0; nt < 2; ++nt){
      int gr0 = i0 + wr + mt*16 + q*4;
      int gc = j0 + wc + nt*16 + m16;
      half4 tv;
      #pragma unroll
      for (int r = 0; r < 4; ++r){
        float v = acc[mt][nt][r];
        if (addA) v += (float)Ab[(size_t)(gr0 + r)*LG + gc];
        f16 hv = (f16)v;
        tv[r] = hv;
        Cb[(size_t)(gr0 + r)*LG + gc] = hv;
      }
      if (iCT >= 0)
        *(half4*)&CT[(size_t)gc*LG + gr0] = tv;
    }
  }
}

// -------- final: y[l,d] = sum_t O[l,t]*s[t]*G[l,t]*x[t,d] + x[l,d]*D[h]
// block: 16 l-rows x one bh; t-chunked coef tile in LDS; thread = (l, d)
__global__ __launch_bounds__(256) void k_final2(char* base, size_t regB, int iO,
    const f16* __restrict__ Gh, const float* __restrict__ sdt,
    const void* __restrict__ x, const void* __restrict__ Dv,
    const int* __restrict__ flag, void* __restrict__ out,
    int b0, int h0, int HB){
  __shared__ float coef[16][257];
  int bh = blockIdx.y;
  int gl = bh / HB, g = b0 + gl, h = h0 + bh % HB;
  int L0r = blockIdx.x*16;
  int tid = threadIdx.x;
  int lr = tid >> 4, ts = tid & 15;   // phase1: (row lr, t-seg ts); phase2: (row lr, d=ts)
  int f32 = *flag;
  const f16* Orow = (const f16*)(base + (size_t)bh*regB) + (size_t)iO*MSZ + (size_t)(L0r+lr)*LG;
  const f16* Grow = Gh + (size_t)gl*MSZ + (size_t)(L0r+lr)*LG;
  const float* srow = sdt + h*NTOT + g*LG;
  float acc = 0.f;
  for (int tc = 0; tc < LG; tc += 256){
    int tb = tc + ts*16;
    __syncthreads();
    half8 o0 = *(const half8*)&Orow[tb];
    half8 o1 = *(const half8*)&Orow[tb + 8];
    half8 g0 = *(const half8*)&Grow[tb];
    half8 g1 = *(const half8*)&Grow[tb + 8];
    #pragma unroll
    for (int j = 0; j < 8; ++j){
      coef[lr][ts*16 + j]     = (float)o0[j] * (float)g0[j] * srow[tb + j];
      coef[lr][ts*16 + 8 + j] = (float)o1[j] * (float)g1[j] * srow[tb + 8 + j];
    }
    __syncthreads();
    if (f32){
      const float* xf = (const float*)x + (size_t)(g*LG + tc)*128 + h*HD + ts;
      for (int t = 0; t < 256; ++t)
        acc = fmaf(coef[lr][t], xf[(size_t)t*128], acc);
    } else {
      const bf16* xb = (const bf16*)x + (size_t)(g*LG + tc)*128 + h*HD + ts;
      for (int t = 0; t < 256; ++t)
        acc = fmaf(coef[lr][t], b2f(xb[(size_t)t*128]), acc);
    }
  }
  int l = L0r + lr, d = ts;
  float xs = ldv(x, (size_t)(g*LG + l)*128 + h*HD + d, f32);
  float dv = ldv(Dv, h, f32);
  float v = acc + xs*dv;
  size_t off = (size_t)(g*LG + l)*128 + d*H_ + h;
  if (f32) ((float*)out)[off] = v;
  else     ((bf16*)out)[off] = __float2bfloat16(v);
}

extern "C" void kernel_launch(void* const* d_in, const int* in_sizes, int n_in,
                              void* d_out, int out_size, void* d_ws, size_t ws_size,
                              hipStream_t stream){
  const void* x   = d_in[0];
  const void* Bm  = d_in[1];
  const void* Cm  = d_in[2];
  const void* dt  = d_in[3];
  const void* dtb = d_in[4];
  const void* Dv  = d_in[5];
  const int*  ei  = (const int*)d_in[6];
  int Etot = in_sizes[6] / 2;  // 131072

  // per-(b,h) chain region: 6 f16 matrices (12 MB):
  //   slots 0-3: L/LT ping-pong pairs, 4,5: O ping/pong
  //   fp32 scatter buffer (4 MB) aliases slots 2+3 (dead before first GEMM writes them)
  const size_t REG = (size_t)6*MSZ*2;  // bytes
  int GB = 1, HB = 1;
  const int cfgs[7][2] = {{8,8},{4,8},{2,8},{1,8},{1,4},{1,2},{1,1}};
  for (int i = 0; i < 7; ++i){
    int gb = cfgs[i][0], hb = cfgs[i][1];
    size_t need = 4ull*(4ull*H_*NTOT + 64)           // coeffs + flag
                + 4ull*(size_t)gb*hb*LG              // nrm
                + 2ull*(size_t)gb*MSZ                // G (f16)
                + (size_t)gb*hb*REG;                 // chain regions
    if (need <= ws_size){ GB = gb; HB = hb; break; }
  }
  int lgHB = (HB==8)?3:((HB==4)?2:((HB==2)?1:0));
  int nbh = GB*HB;

  float* a0  = (float*)d_ws;
  float* a1  = a0 + H_*NTOT;
  float* dum = a1 + H_*NTOT;
  float* sdt = dum + H_*NTOT;
  int*  flag = (int*)(sdt + H_*NTOT);
  float* nrm = (float*)flag + 64;
  f16* G     = (f16*)(nrm + (size_t)nbh*LG);
  char* chainBase = (char*)(G + (size_t)GB*MSZ);

  k_sniff<<<1, 256, 0, stream>>>(dt, flag);
  k_nodecoef<<<(H_*NTOT + 255)/256, 256, 0, stream>>>(dt, dtb, flag, a0, a1, dum, sdt);

  for (int b0 = 0; b0 < BN; b0 += GB){
    for (int h0 = 0; h0 < H_; h0 += HB){
      k_zero<<<dim3(1024, nbh), 256, 0, stream>>>(chainBase, REG);
      (void)hipMemsetAsync(nrm, 0, (size_t)nbh*LG*sizeof(float), stream);
      int nthr = GB*EPG*HB;
      k_scatter<<<(nthr + 255)/256, 256, 0, stream>>>(ei, a0, a1, chainBase, REG, nrm,
                                                      b0, h0, lgHB, GB, nthr, Etot);
      k_normalize<<<nbh*(MSZ/256), 256, 0, stream>>>(chainBase, REG, nrm, dum, b0, h0, HB);
      k_transpose<<<dim3(32, 32, nbh), 256, 0, stream>>>(chainBase, REG, 0, 1);
      if (h0 == 0){
        dim3 gg(64, 64, GB);
        k_G<<<gg, 256, 0, stream>>>(Bm, Cm, flag, G, b0);
      }
      // chain schedule: S0; {S_{k+1}, U_k} fused x4; U_4.
      // S: L' = L@L (writes C and C^T).  U: O' = O@L' + O (B-operand = L'^T).
      int lA = 0, lAT = 1, lC = 2, lCT = 3, oA = 4, oC = 5;
      {
        int T = nbh;
        dim3 gg(8, 64, (T + 7)/8);
        k_gemm_fused<<<gg, 512, 0, stream>>>(chainBase, REG, nbh, lA, lAT, lC, lCT,
                                             0, 0, 0, 0);
      }
      for (int k = 0; k < 4; ++k){
        int T = 2*nbh;
        dim3 gg(8, 64, (T + 7)/8);
        k_gemm_fused<<<gg, 512, 0, stream>>>(chainBase, REG,
                                             nbh, lC, lCT, lA, lAT,    // S_{k+1}
                                             nbh, oA, lCT, oC);        // U_k
        int tp;
        tp = lA; lA = lC; lC = tp;
        tp = lAT; lAT = lCT; lCT = tp;
        tp = oA; oA = oC; oC = tp;
      }
      {
        int T = nbh;
        dim3 gg(8, 64, (T + 7)/8);
        k_gemm_fused<<<gg, 512, 0, stream>>>(chainBase, REG, 0, 0, 0, 0, 0,
                                             nbh, oA, lCT, oC);        // U_4
        int tp = oA; oA = oC; oC = tp;
      }
      dim3 fg(64, nbh);
      k_final2<<<fg, 256, 0, stream>>>(chainBase, REG, oA, G, sdt, x, Dv, flag, d_out, b0, h0, HB);
    }
  }
}

// Round 12
// 2593.386 us; speedup vs baseline: 1.0554x; 1.0554x over previous
//
#include <hip/hip_runtime.h>
#include <hip/hip_bf16.h>

#define H_ 8
#define NTOT 8192
#define LG 1024
#define BN 8
#define HD 16
#define DSTATE 64
#define EPG 16384
#define MSZ (1024*1024)

typedef __hip_bfloat16 bf16;
typedef unsigned short ushort_t;
typedef _Float16 f16;
typedef __attribute__((ext_vector_type(8))) _Float16 half8;
typedef __attribute__((ext_vector_type(4))) _Float16 half4;
typedef __attribute__((ext_vector_type(4))) float f4v;

__device__ __forceinline__ float b2f(bf16 v){ return __bfloat162float(v); }
// stable softplus matching jax.nn.softplus = log1p(exp(z))
__device__ __forceinline__ float sp_(float z){
  return fmaxf(z, 0.f) + log1pf(expf(-fabsf(z)));
}
// dtype-flagged scalar load (uniform branch)
__device__ __forceinline__ float ldv(const void* p, size_t i, int f32){
  float v;
  if (f32) v = ((const float*)p)[i];
  else     v = b2f(((const bf16*)p)[i]);
  return v;
}
// async global->LDS, 16 bytes per lane
__device__ __forceinline__ void gl2lds16(const void* g, void* l){
  __builtin_amdgcn_global_load_lds((const __attribute__((address_space(1))) unsigned int*)g,
                                   (__attribute__((address_space(3))) unsigned int*)l,
                                   16, 0, 0);
}

// -------- dtype sniffer: bf16 N(0,1) data never has exponent>=140; f32-as-bf16 does.
__global__ void k_sniff(const void* __restrict__ dt, int* __restrict__ flag){
  const ushort_t* p = (const ushort_t*)dt;
  int tid = threadIdx.x;
  int bad = 0;
  for (int i = tid; i < 512; i += 256){
    int e = (p[i] >> 7) & 0xFF;
    if (e >= 140) bad = 1;
  }
  unsigned long long m = __ballot(bad != 0);
  __shared__ int anybad[4];
  if ((tid & 63) == 0) anybad[tid >> 6] = (m != 0ull) ? 1 : 0;
  __syncthreads();
  if (tid == 0) *flag = (anybad[0] | anybad[1] | anybad[2] | anybad[3]);
}

// -------- per-node coefficients. a0/a1 stored [n][h] (coalesced for k_scatter);
// dum/sdt stay [h][n] (coalesced for k_norm2/k_final3).
__global__ void k_nodecoef(const void* __restrict__ dt, const void* __restrict__ dtb,
                           const int* __restrict__ flag,
                           float* __restrict__ a0, float* __restrict__ a1,
                           float* __restrict__ dum, float* __restrict__ sdt){
  int idx = blockIdx.x*256 + threadIdx.x;
  if (idx >= H_*NTOT) return;
  int f32 = *flag;
  int h = idx / NTOT, n = idx - h*NTOT;
  float bias = ldv(dtb, h, f32);
  size_t base = (size_t)n*(4*H_) + h*4;
  float d0, d1, d2, d3;
  if (f32){
    const float* row = (const float*)dt + base;
    d0 = row[0]; d1 = row[1]; d2 = row[2]; d3 = row[3];
  } else {
    const bf16* row = (const bf16*)dt + base;
    d0 = b2f(row[0]); d1 = b2f(row[1]); d2 = b2f(row[2]); d3 = b2f(row[3]);
  }
  a0[(size_t)n*H_ + h] = -sp_(d0 + bias);
  a1[(size_t)n*H_ + h] = -sp_(d1 + bias);
  dum[idx] = expf(-sp_(d2 + bias));
  sdt[idx] = d3;
}

// -------- zero the per-bh fp32 scatter buffers (aliased at f16 matrix slots 2,3)
// plus the per-bh nrm row (x-block 1024).
__global__ __launch_bounds__(256) void k_zero(char* base, size_t regB, float* __restrict__ nrm){
  int bh = blockIdx.y;
  if (blockIdx.x < 1024){
    float* Mf = (float*)(base + (size_t)bh*regB) + MSZ;
    int i = blockIdx.x*1024 + threadIdx.x*4;
    *(float4*)(Mf + i) = make_float4(0.f,0.f,0.f,0.f);
  } else {
    int j = threadIdx.x*4;
    *(float4*)(nrm + (size_t)bh*LG + j) = make_float4(0.f,0.f,0.f,0.f);
  }
}

// -------- scatter edges into fp32 M = A^T (M[dl][sl] += attr), plus row-sum of A over sl
__global__ void k_scatter(const int* __restrict__ ei, const float* __restrict__ a0,
                          const float* __restrict__ a1, char* base, size_t regB,
                          float* __restrict__ nrm,
                          int b0, int h0, int lgHB, int GBp, int nthreads, int Etot){
  int t = blockIdx.x*256 + threadIdx.x;
  if (t >= nthreads) return;
  int HB = 1 << lgHB;
  int hl = t & (HB-1);
  int el = t >> lgHB;
  int e = b0*EPG + el;
  int src = ei[e], dst = ei[Etot + e];
  int g = src >> 10;
  if ((unsigned)(g - b0) >= (unsigned)GBp) return;
  int sl = src & 1023, dl = dst & 1023;
  int h = h0 + hl;
  float attr = expf(0.5f*(a0[(size_t)src*H_ + h] + a1[(size_t)dst*H_ + h]));
  int bhl = (g - b0)*HB + hl;
  float* Mf = (float*)(base + (size_t)bhl*regB) + MSZ;
  atomicAdd(&Mf[(size_t)dl*LG + sl], attr);
  atomicAdd(&nrm[bhl*LG + sl], attr);
}

// -------- fused normalize + transpose (32x32 tiles): from fp32 M write
// f16 L0 (slot 0), L0^T (slot 1), O0 = I+M (slot 4) in one pass.
__global__ __launch_bounds__(256) void k_norm2(char* base, size_t regB,
                            const float* __restrict__ nrm, const float* __restrict__ dum,
                            int b0, int h0, int HB){
  __shared__ ushort_t tb[32][33];
  int bh = blockIdx.z;
  int g = b0 + bh / HB, h = h0 + bh % HB;
  const float* Mf = (const float*)(base + (size_t)bh*regB) + MSZ;
  f16* L0  = (f16*)(base + (size_t)bh*regB);
  f16* L0T = L0 + MSZ;
  f16* O0  = L0 + (size_t)4*MSZ;
  int x0 = blockIdx.x*32, y0 = blockIdx.y*32;   // x: sl, y: dl
  int tx = threadIdx.x & 31, ty = threadIdx.x >> 5;  // 32 x 8
  int sl = x0 + tx;
  float denom = nrm[(size_t)bh*LG + sl] + dum[(size_t)h*NTOT + g*LG + sl] + 0.1f;
  float rden = 1.f / denom;
  #pragma unroll
  for (int i = 0; i < 32; i += 8){
    int dl = y0 + ty + i;
    float v = Mf[(size_t)dl*LG + sl] * rden;
    f16 hv = (f16)v;
    L0[(size_t)dl*LG + sl] = hv;
    O0[(size_t)dl*LG + sl] = (f16)(v + (dl == sl ? 1.f : 0.f));
    union { f16 h; ushort_t u; } cv; cv.h = hv;
    tb[tx][ty + i] = cv.u;                 // [sl-local][dl-local]
  }
  __syncthreads();
  #pragma unroll
  for (int i = 0; i < 32; i += 8){
    union { f16 h; ushort_t u; } cv; cv.u = tb[ty + i][tx];
    L0T[(size_t)(x0 + ty + i)*LG + y0 + tx] = cv.h;   // L0T[sl][dl]
  }
}

// -------- G[b][l][t] = sum_d C[b,l,d]*B[b,t,d]  -> stored f16
__global__ __launch_bounds__(256) void k_G(const void* __restrict__ Bm, const void* __restrict__ Cm,
                                           const int* __restrict__ flag,
                                           f16* __restrict__ G, int b0){
  int gl = blockIdx.z;
  int g = b0 + gl;
  int l0 = blockIdx.y*16, t0 = blockIdx.x*16;
  __shared__ float Cs[16][DSTATE+1];
  __shared__ float Bs[16][DSTATE+1];
  int tid = threadIdx.x;
  int f32 = *flag;
  if (f32){
    const float* Cf = (const float*)Cm;
    const float* Bf = (const float*)Bm;
    for (int i = tid; i < 16*DSTATE; i += 256){
      int r = i >> 6, d = i & 63;
      Cs[r][d] = Cf[(size_t)(g*LG + l0 + r)*DSTATE + d];
      Bs[r][d] = Bf[(size_t)(g*LG + t0 + r)*DSTATE + d];
    }
  } else {
    const bf16* Cb = (const bf16*)Cm;
    const bf16* Bb = (const bf16*)Bm;
    for (int i = tid; i < 16*DSTATE; i += 256){
      int r = i >> 6, d = i & 63;
      Cs[r][d] = b2f(Cb[(size_t)(g*LG + l0 + r)*DSTATE + d]);
      Bs[r][d] = b2f(Bb[(size_t)(g*LG + t0 + r)*DSTATE + d]);
    }
  }
  __syncthreads();
  int r = tid >> 4, c = tid & 15;
  float acc = 0.f;
  #pragma unroll
  for (int d = 0; d < DSTATE; ++d) acc = fmaf(Cs[r][d], Bs[c][d], acc);
  G[(size_t)gl*MSZ + (size_t)(l0+r)*LG + t0 + c] = (f16)acc;
}

// -------- fused f16 MFMA GEMM dispatch (r10: best measured — FROZEN):
// slices [0,nS) run S (square: C = A@B, writes C and C^T), slices [nS,nS+nU) run
// U (C = A@B + A). B given via its transpose slot. 128x128 block tile, 512 threads =
// 8 waves x 64x32 tiles; 32KB double-buffered LDS -> 5 blocks/CU (80% occupancy).
// BK=32, global_load_lds staging, one barrier per k-iter. XOR swizzle: 0 conflicts.
__global__ __launch_bounds__(512, 6) void k_gemm_fused(char* base, size_t regB,
    int nS, int iAs, int iBTs, int iCs, int iCTs,
    int nU, int iAu, int iBTu, int iCu){
  __shared__ ushort_t As[2][4096];   // [buf][128 rows x 32 k] (swizzled slots)
  __shared__ ushort_t Bs[2][4096];
  int T = nS + nU;
  int s = blockIdx.x + 8*blockIdx.z;
  if (s >= T) return;
  int isS = (s < nS) ? 1 : 0;
  int bh  = isS ? s : (s - nS);
  int iA  = isS ? iAs : iAu;
  int iBT = isS ? iBTs : iBTu;
  int iC  = isS ? iCs : iCu;
  int iCT = isS ? iCTs : -1;
  int addA = 1 - isS;
  char* reg = base + (size_t)bh*regB;
  const f16* Ab = (const f16*)reg + (size_t)iA*MSZ;
  const f16* Bb = (const f16*)reg + (size_t)iBT*MSZ;
  f16* Cb = (f16*)reg + (size_t)iC*MSZ;
  int y = blockIdx.y;
  int i0 = (y >> 3)*128, j0 = (y & 7)*128;
  int tid = threadIdx.x;
  int lane = tid & 63, wv = tid >> 6;       // 8 waves
  int wr = (wv >> 2)*64, wc = (wv & 3)*32;  // wave tile: 64 rows x 32 cols
  int m16 = lane & 15, q = lane >> 4;
  int srow = tid >> 2;
  int skq = (tid & 3) ^ ((tid >> 3) & 3);
  const f16* Ag = Ab + (size_t)(i0 + srow)*LG + skq*8;
  const f16* Bg = Bb + (size_t)(j0 + srow)*LG + skq*8;
  #define STAGE(K0, BUF) do { \
    gl2lds16(Ag + (K0), &As[BUF][(size_t)tid*8]); \
    gl2lds16(Bg + (K0), &Bs[BUF][(size_t)tid*8]); } while(0)
  STAGE(0, 0);
  f4v acc[4][2] = {};
  int slotq = q ^ ((m16 >> 1) & 3);         // swizzled slot holding k-chunk q (lane-constant)
  int aoff = (wr + m16)*32 + slotq*8;       // + t*512 per 16-row tile t
  int boff = (wc + m16)*32 + slotq*8;
  for (int k0 = 0; k0 < LG; k0 += 32){
    int cur = (k0 >> 5) & 1;
    __syncthreads();                        // buf 'cur' staged; prev buf's reads closed
    if (k0 + 32 < LG) STAGE(k0 + 32, cur ^ 1);   // lands during this iter's compute
    half8 af[4], bfr[2];
    #pragma unroll
    for (int t = 0; t < 4; ++t)
      af[t]  = *(const half8*)&As[cur][aoff + t*512];
    #pragma unroll
    for (int t = 0; t < 2; ++t)
      bfr[t] = *(const half8*)&Bs[cur][boff + t*512];
    #pragma unroll
    for (int mt = 0; mt < 4; ++mt)
      #pragma unroll
      for (int nt = 0; nt < 2; ++nt)
        acc[mt][nt] = __builtin_amdgcn_mfma_f32_16x16x32_f16(af[mt], bfr[nt], acc[mt][nt], 0, 0, 0);
  }
  #undef STAGE
  f16* CT = (f16*)reg + (size_t)((iCT < 0) ? iC : iCT)*MSZ;
  // epilogue: D lane mapping col=lane&15, row=(lane>>4)*4+r
  #pragma unroll
  for (int mt = 0; mt < 4; ++mt){
    #pragma unroll
    for (int nt = 0; nt < 2; ++nt){
      int gr0 = i0 + wr + mt*16 + q*4;
      int gc = j0 + wc + nt*16 + m16;
      half4 tv;
      #pragma unroll
      for (int r = 0; r < 4; ++r){
        float v = acc[mt][nt][r];
        if (addA) v += (float)Ab[(size_t)(gr0 + r)*LG + gc];
        f16 hv = (f16)v;
        tv[r] = hv;
        Cb[(size_t)(gr0 + r)*LG + gc] = hv;
      }
      if (iCT >= 0)
        *(half4*)&CT[(size_t)gc*LG + gr0] = tv;
    }
  }
}

// -------- final stage A: partial sums. Block = 16 l-rows x one t-half x one bh.
// Writes fp32 partials to the dead chain slot 0 of this bh: FS[th][l][16].
__global__ __launch_bounds__(256) void k_final3(char* base, size_t regB, int iO,
    const f16* __restrict__ Gh, const float* __restrict__ sdt,
    const void* __restrict__ x, const int* __restrict__ flag,
    int b0, int h0, int HB){
  __shared__ float coef[16][257];
  __shared__ float red[256];
  int bh = blockIdx.y;
  int gl = bh / HB, g = b0 + gl, h = h0 + bh % HB;
  int lb = blockIdx.x >> 1, th = blockIdx.x & 1;
  int L0r = lb*16;
  int tid = threadIdx.x;
  int lr = tid >> 4, ts = tid & 15;
  int f32 = *flag;
  char* reg = base + (size_t)bh*regB;
  const f16* Orow = (const f16*)reg + (size_t)iO*MSZ + (size_t)(L0r+lr)*LG;
  const f16* Grow = Gh + (size_t)gl*MSZ + (size_t)(L0r+lr)*LG;
  const float* srow = sdt + (size_t)h*NTOT + g*LG;
  float* FS = (float*)reg;                      // slot 0 (dead L matrix) as staging
  float acc = 0.f;
  for (int tc = th*512; tc < th*512 + 512; tc += 256){
    int tb = tc + ts*16;
    __syncthreads();
    half8 o0 = *(const half8*)&Orow[tb];
    half8 o1 = *(const half8*)&Orow[tb + 8];
    half8 g0 = *(const half8*)&Grow[tb];
    half8 g1 = *(const half8*)&Grow[tb + 8];
    #pragma unroll
    for (int j = 0; j < 8; ++j){
      coef[lr][ts*16 + j]     = (float)o0[j] * (float)g0[j] * srow[tb + j];
      coef[lr][ts*16 + 8 + j] = (float)o1[j] * (float)g1[j] * srow[tb + 8 + j];
    }
    __syncthreads();
    if (f32){
      const float* xf = (const float*)x + (size_t)(g*LG + tc)*128 + h*HD + ts;
      for (int t = 0; t < 256; ++t)
        acc = fmaf(coef[lr][t], xf[(size_t)t*128], acc);
    } else {
      const bf16* xb = (const bf16*)x + (size_t)(g*LG + tc)*128 + h*HD + ts;
      for (int t = 0; t < 256; ++t)
        acc = fmaf(coef[lr][t], b2f(xb[(size_t)t*128]), acc);
    }
  }
  red[tid] = acc;
  __syncthreads();
  // no reduction across lr needed: each (lr,ts) owns (l = L0r+lr, d = ts) fully
  FS[(size_t)th*16384 + (size_t)(L0r + lr)*16 + ts] = red[tid];
}

// -------- final stage B: combine halves + residual, write output.
__global__ __launch_bounds__(256) void k_out(char* base, size_t regB,
    const void* __restrict__ x, const void* __restrict__ Dv,
    const int* __restrict__ flag, void* __restrict__ out,
    int b0, int h0, int HB, int nbh){
  int idx = blockIdx.x*256 + threadIdx.x;
  if (idx >= nbh*LG*16) return;
  int d = idx & 15;
  int l = (idx >> 4) & 1023;
  int bh = idx >> 14;
  int g = b0 + bh / HB, h = h0 + bh % HB;
  int f32 = *flag;
  const float* FS = (const float*)(base + (size_t)bh*regB);
  float v = FS[(size_t)l*16 + d] + FS[16384 + (size_t)l*16 + d];
  float xs = ldv(x, (size_t)(g*LG + l)*128 + h*HD + d, f32);
  float dv = ldv(Dv, h, f32);
  v += xs * dv;
  size_t off = (size_t)(g*LG + l)*128 + d*H_ + h;
  if (f32) ((float*)out)[off] = v;
  else     ((bf16*)out)[off] = __float2bfloat16(v);
}

extern "C" void kernel_launch(void* const* d_in, const int* in_sizes, int n_in,
                              void* d_out, int out_size, void* d_ws, size_t ws_size,
                              hipStream_t stream){
  const void* x   = d_in[0];
  const void* Bm  = d_in[1];
  const void* Cm  = d_in[2];
  const void* dt  = d_in[3];
  const void* dtb = d_in[4];
  const void* Dv  = d_in[5];
  const int*  ei  = (const int*)d_in[6];
  int Etot = in_sizes[6] / 2;  // 131072

  // per-(b,h) chain region: 6 f16 matrices (12 MB):
  //   slots 0-3: L/LT ping-pong pairs, 4,5: O ping/pong
  //   fp32 scatter buffer (4 MB) aliases slots 2+3; fp32 final-staging (128 KB)
  //   aliases slot 0 (dead after last S).
  const size_t REG = (size_t)6*MSZ*2;  // bytes
  int GB = 1, HB = 1;
  const int cfgs[7][2] = {{8,8},{4,8},{2,8},{1,8},{1,4},{1,2},{1,1}};
  for (int i = 0; i < 7; ++i){
    int gb = cfgs[i][0], hb = cfgs[i][1];
    size_t need = 4ull*(4ull*H_*NTOT + 64)           // coeffs + flag
                + 4ull*(size_t)gb*hb*LG              // nrm
                + 2ull*(size_t)gb*MSZ                // G (f16)
                + (size_t)gb*hb*REG;                 // chain regions
    if (need <= ws_size){ GB = gb; HB = hb; break; }
  }
  int lgHB = (HB==8)?3:((HB==4)?2:((HB==2)?1:0));
  int nbh = GB*HB;

  float* a0  = (float*)d_ws;
  float* a1  = a0 + H_*NTOT;
  float* dum = a1 + H_*NTOT;
  float* sdt = dum + H_*NTOT;
  int*  flag = (int*)(sdt + H_*NTOT);
  float* nrm = (float*)flag + 64;
  f16* G     = (f16*)(nrm + (size_t)nbh*LG);
  char* chainBase = (char*)(G + (size_t)GB*MSZ);

  k_sniff<<<1, 256, 0, stream>>>(dt, flag);
  k_nodecoef<<<(H_*NTOT + 255)/256, 256, 0, stream>>>(dt, dtb, flag, a0, a1, dum, sdt);

  for (int b0 = 0; b0 < BN; b0 += GB){
    for (int h0 = 0; h0 < H_; h0 += HB){
      k_zero<<<dim3(1025, nbh), 256, 0, stream>>>(chainBase, REG, nrm);
      int nthr = GB*EPG*HB;
      k_scatter<<<(nthr + 255)/256, 256, 0, stream>>>(ei, a0, a1, chainBase, REG, nrm,
                                                      b0, h0, lgHB, GB, nthr, Etot);
      k_norm2<<<dim3(32, 32, nbh), 256, 0, stream>>>(chainBase, REG, nrm, dum, b0, h0, HB);
      if (h0 == 0){
        dim3 gg(64, 64, GB);
        k_G<<<gg, 256, 0, stream>>>(Bm, Cm, flag, G, b0);
      }
      // chain schedule: S0; {S_{k+1}, U_k} fused x4; U_4.
      // S: L' = L@L (writes C and C^T).  U: O' = O@L' + O (B-operand = L'^T).
      int lA = 0, lAT = 1, lC = 2, lCT = 3, oA = 4, oC = 5;
      {
        int T = nbh;
        dim3 gg(8, 64, (T + 7)/8);
        k_gemm_fused<<<gg, 512, 0, stream>>>(chainBase, REG, nbh, lA, lAT, lC, lCT,
                                             0, 0, 0, 0);
      }
      for (int k = 0; k < 4; ++k){
        int T = 2*nbh;
        dim3 gg(8, 64, (T + 7)/8);
        k_gemm_fused<<<gg, 512, 0, stream>>>(chainBase, REG,
                                             nbh, lC, lCT, lA, lAT,    // S_{k+1}
                                             nbh, oA, lCT, oC);        // U_k
        int tp;
        tp = lA; lA = lC; lC = tp;
        tp = lAT; lAT = lCT; lCT = tp;
        tp = oA; oA = oC; oC = tp;
      }
      {
        int T = nbh;
        dim3 gg(8, 64, (T + 7)/8);
        k_gemm_fused<<<gg, 512, 0, stream>>>(chainBase, REG, 0, 0, 0, 0, 0,
                                             nbh, oA, lCT, oC);        // U_4
        int tp = oA; oA = oC; oC = tp;
      }
      // finals: partial sums into slot-0 staging (slot 0 = dead L buffer here),
      // then combine + residual + store.
      dim3 fg(128, nbh);
      k_final3<<<fg, 256, 0, stream>>>(chainBase, REG, oA, G, sdt, x, flag, b0, h0, HB);
      int nout = nbh*LG*16;
      k_out<<<(nout + 255)/256, 256, 0, stream>>>(chainBase, REG, x, Dv, flag, d_out,
                                                  b0, h0, HB, nbh);
    }
  }
}

// Round 13
// 2374.180 us; speedup vs baseline: 1.1529x; 1.0923x over previous
//
#include <hip/hip_runtime.h>
#include <hip/hip_bf16.h>

#define H_ 8
#define NTOT 8192
#define LG 1024
#define BN 8
#define HD 16
#define DSTATE 64
#define EPG 16384
#define MSZ (1024*1024)

typedef __hip_bfloat16 bf16;
typedef unsigned short ushort_t;
typedef _Float16 f16;
typedef __attribute__((ext_vector_type(8))) _Float16 half8;
typedef __attribute__((ext_vector_type(4))) _Float16 half4;
typedef __attribute__((ext_vector_type(4))) float f4v;

__device__ __forceinline__ float b2f(bf16 v){ return __bfloat162float(v); }
// stable softplus matching jax.nn.softplus = log1p(exp(z))
__device__ __forceinline__ float sp_(float z){
  return fmaxf(z, 0.f) + log1pf(expf(-fabsf(z)));
}
// dtype-flagged scalar load (uniform branch)
__device__ __forceinline__ float ldv(const void* p, size_t i, int f32){
  float v;
  if (f32) v = ((const float*)p)[i];
  else     v = b2f(((const bf16*)p)[i]);
  return v;
}
// async global->LDS, 16 bytes per lane
__device__ __forceinline__ void gl2lds16(const void* g, void* l){
  __builtin_amdgcn_global_load_lds((const __attribute__((address_space(1))) unsigned int*)g,
                                   (__attribute__((address_space(3))) unsigned int*)l,
                                   16, 0, 0);
}

// -------- dtype sniffer: bf16 N(0,1) data never has exponent>=140; f32-as-bf16 does.
__global__ void k_sniff(const void* __restrict__ dt, int* __restrict__ flag){
  const ushort_t* p = (const ushort_t*)dt;
  int tid = threadIdx.x;
  int bad = 0;
  for (int i = tid; i < 512; i += 256){
    int e = (p[i] >> 7) & 0xFF;
    if (e >= 140) bad = 1;
  }
  unsigned long long m = __ballot(bad != 0);
  __shared__ int anybad[4];
  if ((tid & 63) == 0) anybad[tid >> 6] = (m != 0ull) ? 1 : 0;
  __syncthreads();
  if (tid == 0) *flag = (anybad[0] | anybad[1] | anybad[2] | anybad[3]);
}

// -------- per-node coefficients. a0/a1 stored [n][h] (coalesced for k_scatter);
// dum/sdt stay [h][n] (coalesced for k_norm2/k_final2).
__global__ void k_nodecoef(const void* __restrict__ dt, const void* __restrict__ dtb,
                           const int* __restrict__ flag,
                           float* __restrict__ a0, float* __restrict__ a1,
                           float* __restrict__ dum, float* __restrict__ sdt){
  int idx = blockIdx.x*256 + threadIdx.x;
  if (idx >= H_*NTOT) return;
  int f32 = *flag;
  int h = idx / NTOT, n = idx - h*NTOT;
  float bias = ldv(dtb, h, f32);
  size_t base = (size_t)n*(4*H_) + h*4;
  float d0, d1, d2, d3;
  if (f32){
    const float* row = (const float*)dt + base;
    d0 = row[0]; d1 = row[1]; d2 = row[2]; d3 = row[3];
  } else {
    const bf16* row = (const bf16*)dt + base;
    d0 = b2f(row[0]); d1 = b2f(row[1]); d2 = b2f(row[2]); d3 = b2f(row[3]);
  }
  a0[(size_t)n*H_ + h] = -sp_(d0 + bias);
  a1[(size_t)n*H_ + h] = -sp_(d1 + bias);
  dum[idx] = expf(-sp_(d2 + bias));
  sdt[idx] = d3;
}

// -------- zero the per-bh fp32 scatter buffers (aliased at f16 matrix slots 2,3)
// plus the per-bh nrm row (x-block 1024).
__global__ __launch_bounds__(256) void k_zero(char* base, size_t regB, float* __restrict__ nrm){
  int bh = blockIdx.y;
  if (blockIdx.x < 1024){
    float* Mf = (float*)(base + (size_t)bh*regB) + MSZ;
    int i = blockIdx.x*1024 + threadIdx.x*4;
    *(float4*)(Mf + i) = make_float4(0.f,0.f,0.f,0.f);
  } else {
    int j = threadIdx.x*4;
    *(float4*)(nrm + (size_t)bh*LG + j) = make_float4(0.f,0.f,0.f,0.f);
  }
}

// -------- scatter edges into fp32 M = A^T (M[dl][sl] += attr), plus row-sum of A over sl
__global__ void k_scatter(const int* __restrict__ ei, const float* __restrict__ a0,
                          const float* __restrict__ a1, char* base, size_t regB,
                          float* __restrict__ nrm,
                          int b0, int h0, int lgHB, int GBp, int nthreads, int Etot){
  int t = blockIdx.x*256 + threadIdx.x;
  if (t >= nthreads) return;
  int HB = 1 << lgHB;
  int hl = t & (HB-1);
  int el = t >> lgHB;
  int e = b0*EPG + el;
  int src = ei[e], dst = ei[Etot + e];
  int g = src >> 10;
  if ((unsigned)(g - b0) >= (unsigned)GBp) return;
  int sl = src & 1023, dl = dst & 1023;
  int h = h0 + hl;
  float attr = expf(0.5f*(a0[(size_t)src*H_ + h] + a1[(size_t)dst*H_ + h]));
  int bhl = (g - b0)*HB + hl;
  float* Mf = (float*)(base + (size_t)bhl*regB) + MSZ;
  atomicAdd(&Mf[(size_t)dl*LG + sl], attr);
  atomicAdd(&nrm[bhl*LG + sl], attr);
}

// -------- fused normalize + transpose (32x32 tiles): from fp32 M write
// f16 L0 (slot 0), L0^T (slot 1), O0 = I+M (slot 4) in one pass.
__global__ __launch_bounds__(256) void k_norm2(char* base, size_t regB,
                            const float* __restrict__ nrm, const float* __restrict__ dum,
                            int b0, int h0, int HB){
  __shared__ ushort_t tb[32][33];
  int bh = blockIdx.z;
  int g = b0 + bh / HB, h = h0 + bh % HB;
  const float* Mf = (const float*)(base + (size_t)bh*regB) + MSZ;
  f16* L0  = (f16*)(base + (size_t)bh*regB);
  f16* L0T = L0 + MSZ;
  f16* O0  = L0 + (size_t)4*MSZ;
  int x0 = blockIdx.x*32, y0 = blockIdx.y*32;   // x: sl, y: dl
  int tx = threadIdx.x & 31, ty = threadIdx.x >> 5;  // 32 x 8
  int sl = x0 + tx;
  float denom = nrm[(size_t)bh*LG + sl] + dum[(size_t)h*NTOT + g*LG + sl] + 0.1f;
  float rden = 1.f / denom;
  #pragma unroll
  for (int i = 0; i < 32; i += 8){
    int dl = y0 + ty + i;
    float v = Mf[(size_t)dl*LG + sl] * rden;
    f16 hv = (f16)v;
    L0[(size_t)dl*LG + sl] = hv;
    O0[(size_t)dl*LG + sl] = (f16)(v + (dl == sl ? 1.f : 0.f));
    union { f16 h; ushort_t u; } cv; cv.h = hv;
    tb[tx][ty + i] = cv.u;                 // [sl-local][dl-local]
  }
  __syncthreads();
  #pragma unroll
  for (int i = 0; i < 32; i += 8){
    union { f16 h; ushort_t u; } cv; cv.u = tb[ty + i][tx];
    L0T[(size_t)(x0 + ty + i)*LG + y0 + tx] = cv.h;   // L0T[sl][dl]
  }
}

// -------- G[b][l][t] = sum_d C[b,l,d]*B[b,t,d]  -> stored f16
__global__ __launch_bounds__(256) void k_G(const void* __restrict__ Bm, const void* __restrict__ Cm,
                                           const int* __restrict__ flag,
                                           f16* __restrict__ G, int b0){
  int gl = blockIdx.z;
  int g = b0 + gl;
  int l0 = blockIdx.y*16, t0 = blockIdx.x*16;
  __shared__ float Cs[16][DSTATE+1];
  __shared__ float Bs[16][DSTATE+1];
  int tid = threadIdx.x;
  int f32 = *flag;
  if (f32){
    const float* Cf = (const float*)Cm;
    const float* Bf = (const float*)Bm;
    for (int i = tid; i < 16*DSTATE; i += 256){
      int r = i >> 6, d = i & 63;
      Cs[r][d] = Cf[(size_t)(g*LG + l0 + r)*DSTATE + d];
      Bs[r][d] = Bf[(size_t)(g*LG + t0 + r)*DSTATE + d];
    }
  } else {
    const bf16* Cb = (const bf16*)Cm;
    const bf16* Bb = (const bf16*)Bm;
    for (int i = tid; i < 16*DSTATE; i += 256){
      int r = i >> 6, d = i & 63;
      Cs[r][d] = b2f(Cb[(size_t)(g*LG + l0 + r)*DSTATE + d]);
      Bs[r][d] = b2f(Bb[(size_t)(g*LG + t0 + r)*DSTATE + d]);
    }
  }
  __syncthreads();
  int r = tid >> 4, c = tid & 15;
  float acc = 0.f;
  #pragma unroll
  for (int d = 0; d < DSTATE; ++d) acc = fmaf(Cs[r][d], Bs[c][d], acc);
  G[(size_t)gl*MSZ + (size_t)(l0+r)*LG + t0 + c] = (f16)acc;
}

// -------- fused f16 MFMA GEMM dispatch (r10: best measured — FROZEN):
// slices [0,nS) run S (square: C = A@B, writes C and C^T), slices [nS,nS+nU) run
// U (C = A@B + A). B given via its transpose slot. 128x128 block tile, 512 threads =
// 8 waves x 64x32 tiles; 32KB double-buffered LDS -> 5 blocks/CU (80% occupancy).
// BK=32, global_load_lds staging, one barrier per k-iter. XOR swizzle: 0 conflicts.
// Plateau note: LDS-BW + barrier bound at ~28% MfmaUtil (~680 TF) — r7/r9/r11
// structural probes all neutral-or-worse; hand-asm territory beyond this.
__global__ __launch_bounds__(512, 6) void k_gemm_fused(char* base, size_t regB,
    int nS, int iAs, int iBTs, int iCs, int iCTs,
    int nU, int iAu, int iBTu, int iCu){
  __shared__ ushort_t As[2][4096];   // [buf][128 rows x 32 k] (swizzled slots)
  __shared__ ushort_t Bs[2][4096];
  int T = nS + nU;
  int s = blockIdx.x + 8*blockIdx.z;
  if (s >= T) return;
  int isS = (s < nS) ? 1 : 0;
  int bh  = isS ? s : (s - nS);
  int iA  = isS ? iAs : iAu;
  int iBT = isS ? iBTs : iBTu;
  int iC  = isS ? iCs : iCu;
  int iCT = isS ? iCTs : -1;
  int addA = 1 - isS;
  char* reg = base + (size_t)bh*regB;
  const f16* Ab = (const f16*)reg + (size_t)iA*MSZ;
  const f16* Bb = (const f16*)reg + (size_t)iBT*MSZ;
  f16* Cb = (f16*)reg + (size_t)iC*MSZ;
  int y = blockIdx.y;
  int i0 = (y >> 3)*128, j0 = (y & 7)*128;
  int tid = threadIdx.x;
  int lane = tid & 63, wv = tid >> 6;       // 8 waves
  int wr = (wv >> 2)*64, wc = (wv & 3)*32;  // wave tile: 64 rows x 32 cols
  int m16 = lane & 15, q = lane >> 4;
  int srow = tid >> 2;
  int skq = (tid & 3) ^ ((tid >> 3) & 3);
  const f16* Ag = Ab + (size_t)(i0 + srow)*LG + skq*8;
  const f16* Bg = Bb + (size_t)(j0 + srow)*LG + skq*8;
  #define STAGE(K0, BUF) do { \
    gl2lds16(Ag + (K0), &As[BUF][(size_t)tid*8]); \
    gl2lds16(Bg + (K0), &Bs[BUF][(size_t)tid*8]); } while(0)
  STAGE(0, 0);
  f4v acc[4][2] = {};
  int slotq = q ^ ((m16 >> 1) & 3);         // swizzled slot holding k-chunk q (lane-constant)
  int aoff = (wr + m16)*32 + slotq*8;       // + t*512 per 16-row tile t
  int boff = (wc + m16)*32 + slotq*8;
  for (int k0 = 0; k0 < LG; k0 += 32){
    int cur = (k0 >> 5) & 1;
    __syncthreads();                        // buf 'cur' staged; prev buf's reads closed
    if (k0 + 32 < LG) STAGE(k0 + 32, cur ^ 1);   // lands during this iter's compute
    half8 af[4], bfr[2];
    #pragma unroll
    for (int t = 0; t < 4; ++t)
      af[t]  = *(const half8*)&As[cur][aoff + t*512];
    #pragma unroll
    for (int t = 0; t < 2; ++t)
      bfr[t] = *(const half8*)&Bs[cur][boff + t*512];
    #pragma unroll
    for (int mt = 0; mt < 4; ++mt)
      #pragma unroll
      for (int nt = 0; nt < 2; ++nt)
        acc[mt][nt] = __builtin_amdgcn_mfma_f32_16x16x32_f16(af[mt], bfr[nt], acc[mt][nt], 0, 0, 0);
  }
  #undef STAGE
  f16* CT = (f16*)reg + (size_t)((iCT < 0) ? iC : iCT)*MSZ;
  // epilogue: D lane mapping col=lane&15, row=(lane>>4)*4+r
  #pragma unroll
  for (int mt = 0; mt < 4; ++mt){
    #pragma unroll
    for (int nt = 0; nt < 2; ++nt){
      int gr0 = i0 + wr + mt*16 + q*4;
      int gc = j0 + wc + nt*16 + m16;
      half4 tv;
      #pragma unroll
      for (int r = 0; r < 4; ++r){
        float v = acc[mt][nt][r];
        if (addA) v += (float)Ab[(size_t)(gr0 + r)*LG + gc];
        f16 hv = (f16)v;
        tv[r] = hv;
        Cb[(size_t)(gr0 + r)*LG + gc] = hv;
      }
      if (iCT >= 0)
        *(half4*)&CT[(size_t)gc*LG + gr0] = tv;
    }
  }
}

// -------- final: y[l,d] = sum_t O[l,t]*s[t]*G[l,t]*x[t,d] + x[l,d]*D[h]
// block: 16 l-rows x one bh; t-chunked coef tile in LDS; thread = (l, d)
// (r10's proven single-pass version — the r12 two-stage split was neutral-to-worse)
__global__ __launch_bounds__(256) void k_final2(char* base, size_t regB, int iO,
    const f16* __restrict__ Gh, const float* __restrict__ sdt,
    const void* __restrict__ x, const void* __restrict__ Dv,
    const int* __restrict__ flag, void* __restrict__ out,
    int b0, int h0, int HB){
  __shared__ float coef[16][257];
  int bh = blockIdx.y;
  int gl = bh / HB, g = b0 + gl, h = h0 + bh % HB;
  int L0r = blockIdx.x*16;
  int tid = threadIdx.x;
  int lr = tid >> 4, ts = tid & 15;   // phase1: (row lr, t-seg ts); phase2: (row lr, d=ts)
  int f32 = *flag;
  const f16* Orow = (const f16*)(base + (size_t)bh*regB) + (size_t)iO*MSZ + (size_t)(L0r+lr)*LG;
  const f16* Grow = Gh + (size_t)gl*MSZ + (size_t)(L0r+lr)*LG;
  const float* srow = sdt + (size_t)h*NTOT + g*LG;
  float acc = 0.f;
  for (int tc = 0; tc < LG; tc += 256){
    int tb = tc + ts*16;
    __syncthreads();
    half8 o0 = *(const half8*)&Orow[tb];
    half8 o1 = *(const half8*)&Orow[tb + 8];
    half8 g0 = *(const half8*)&Grow[tb];
    half8 g1 = *(const half8*)&Grow[tb + 8];
    #pragma unroll
    for (int j = 0; j < 8; ++j){
      coef[lr][ts*16 + j]     = (float)o0[j] * (float)g0[j] * srow[tb + j];
      coef[lr][ts*16 + 8 + j] = (float)o1[j] * (float)g1[j] * srow[tb + 8 + j];
    }
    __syncthreads();
    if (f32){
      const float* xf = (const float*)x + (size_t)(g*LG + tc)*128 + h*HD + ts;
      for (int t = 0; t < 256; ++t)
        acc = fmaf(coef[lr][t], xf[(size_t)t*128], acc);
    } else {
      const bf16* xb = (const bf16*)x + (size_t)(g*LG + tc)*128 + h*HD + ts;
      for (int t = 0; t < 256; ++t)
        acc = fmaf(coef[lr][t], b2f(xb[(size_t)t*128]), acc);
    }
  }
  int l = L0r + lr, d = ts;
  float xs = ldv(x, (size_t)(g*LG + l)*128 + h*HD + d, f32);
  float dv = ldv(Dv, h, f32);
  float v = acc + xs*dv;
  size_t off = (size_t)(g*LG + l)*128 + d*H_ + h;
  if (f32) ((float*)out)[off] = v;
  else     ((bf16*)out)[off] = __float2bfloat16(v);
}

extern "C" void kernel_launch(void* const* d_in, const int* in_sizes, int n_in,
                              void* d_out, int out_size, void* d_ws, size_t ws_size,
                              hipStream_t stream){
  const void* x   = d_in[0];
  const void* Bm  = d_in[1];
  const void* Cm  = d_in[2];
  const void* dt  = d_in[3];
  const void* dtb = d_in[4];
  const void* Dv  = d_in[5];
  const int*  ei  = (const int*)d_in[6];
  int Etot = in_sizes[6] / 2;  // 131072

  // per-(b,h) chain region: 6 f16 matrices (12 MB):
  //   slots 0-3: L/LT ping-pong pairs, 4,5: O ping/pong
  //   fp32 scatter buffer (4 MB) aliases slots 2+3 (dead before first GEMM writes them)
  const size_t REG = (size_t)6*MSZ*2;  // bytes
  int GB = 1, HB = 1;
  const int cfgs[7][2] = {{8,8},{4,8},{2,8},{1,8},{1,4},{1,2},{1,1}};
  for (int i = 0; i < 7; ++i){
    int gb = cfgs[i][0], hb = cfgs[i][1];
    size_t need = 4ull*(4ull*H_*NTOT + 64)           // coeffs + flag
                + 4ull*(size_t)gb*hb*LG              // nrm
                + 2ull*(size_t)gb*MSZ                // G (f16)
                + (size_t)gb*hb*REG;                 // chain regions
    if (need <= ws_size){ GB = gb; HB = hb; break; }
  }
  int lgHB = (HB==8)?3:((HB==4)?2:((HB==2)?1:0));
  int nbh = GB*HB;

  float* a0  = (float*)d_ws;
  float* a1  = a0 + H_*NTOT;
  float* dum = a1 + H_*NTOT;
  float* sdt = dum + H_*NTOT;
  int*  flag = (int*)(sdt + H_*NTOT);
  float* nrm = (float*)flag + 64;
  f16* G     = (f16*)(nrm + (size_t)nbh*LG);
  char* chainBase = (char*)(G + (size_t)GB*MSZ);

  k_sniff<<<1, 256, 0, stream>>>(dt, flag);
  k_nodecoef<<<(H_*NTOT + 255)/256, 256, 0, stream>>>(dt, dtb, flag, a0, a1, dum, sdt);

  for (int b0 = 0; b0 < BN; b0 += GB){
    for (int h0 = 0; h0 < H_; h0 += HB){
      k_zero<<<dim3(1025, nbh), 256, 0, stream>>>(chainBase, REG, nrm);
      int nthr = GB*EPG*HB;
      k_scatter<<<(nthr + 255)/256, 256, 0, stream>>>(ei, a0, a1, chainBase, REG, nrm,
                                                      b0, h0, lgHB, GB, nthr, Etot);
      k_norm2<<<dim3(32, 32, nbh), 256, 0, stream>>>(chainBase, REG, nrm, dum, b0, h0, HB);
      if (h0 == 0){
        dim3 gg(64, 64, GB);
        k_G<<<gg, 256, 0, stream>>>(Bm, Cm, flag, G, b0);
      }
      // chain schedule: S0; {S_{k+1}, U_k} fused x4; U_4.
      // S: L' = L@L (writes C and C^T).  U: O' = O@L' + O (B-operand = L'^T).
      int lA = 0, lAT = 1, lC = 2, lCT = 3, oA = 4, oC = 5;
      {
        int T = nbh;
        dim3 gg(8, 64, (T + 7)/8);
        k_gemm_fused<<<gg, 512, 0, stream>>>(chainBase, REG, nbh, lA, lAT, lC, lCT,
                                             0, 0, 0, 0);
      }
      for (int k = 0; k < 4; ++k){
        int T = 2*nbh;
        dim3 gg(8, 64, (T + 7)/8);
        k_gemm_fused<<<gg, 512, 0, stream>>>(chainBase, REG,
                                             nbh, lC, lCT, lA, lAT,    // S_{k+1}
                                             nbh, oA, lCT, oC);        // U_k
        int tp;
        tp = lA; lA = lC; lC = tp;
        tp = lAT; lAT = lCT; lCT = tp;
        tp = oA; oA = oC; oC = tp;
      }
      {
        int T = nbh;
        dim3 gg(8, 64, (T + 7)/8);
        k_gemm_fused<<<gg, 512, 0, stream>>>(chainBase, REG, 0, 0, 0, 0, 0,
                                             nbh, oA, lCT, oC);        // U_4
        int tp = oA; oA = oC; oC = tp;
      }
      dim3 fg(64, nbh);
      k_final2<<<fg, 256, 0, stream>>>(chainBase, REG, oA, G, sdt, x, Dv, flag, d_out, b0, h0, HB);
    }
  }
}